// Round 6
// 550.014 us; speedup vs baseline: 1.0112x; 1.0112x over previous
//
#include <hip/hip_runtime.h>
#include <hip/hip_bf16.h>
#include <stdint.h>

#define B_ 4096
#define D_ 2048
#define U_ 2048
#define K_ 4096   // D + U
#define N_ 8192   // 4 * U

typedef __bf16 bf16x8 __attribute__((ext_vector_type(8)));
typedef float floatx4 __attribute__((ext_vector_type(4)));
typedef unsigned short ushort8 __attribute__((ext_vector_type(8)));

__device__ __forceinline__ unsigned short f2bf(float f) {
    union { float f; unsigned int u; } v; v.f = f;
    unsigned int u = v.u;
    unsigned int r = (u + 0x7fffu + ((u >> 16) & 1u)) >> 16;  // round-nearest-even
    return (unsigned short)r;
}

__device__ __forceinline__ float bf2f(unsigned short b) {
    union { unsigned int u; float f; } v;
    v.u = ((unsigned int)b) << 16;
    return v.f;
}

__device__ __forceinline__ float sigmoid_(float x) {
    return 1.0f / (1.0f + __expf(-x));
}
__device__ __forceinline__ float tanh_(float x) {
    return 1.0f - 2.0f / (__expf(2.0f * x) + 1.0f);
}

// ---------------------------------------------------------------------------
// Kernel 1: pack [x | h] -> Abf[4096][4096] bf16 (row-major, K contiguous)
// ---------------------------------------------------------------------------
__global__ void k_convA(const float* __restrict__ x, const float* __restrict__ h,
                        unsigned short* __restrict__ Abf) {
    int t = blockIdx.x * blockDim.x + threadIdx.x;   // one float4 each
    long e = (long)t * 4;
    int b = (int)(e >> 12);       // / 4096
    int k = (int)(e & 4095);
    const float* src = (k < D_) ? (x + (size_t)b * D_ + k)
                                : (h + (size_t)b * U_ + (k - D_));
    float4 v = *(const float4*)src;
    ushort4 o;
    o.x = f2bf(v.x); o.y = f2bf(v.y); o.z = f2bf(v.z); o.w = f2bf(v.w);
    *(ushort4*)(Abf + e) = o;
}

// ---------------------------------------------------------------------------
// Kernel 2: transpose weights -> Bt[8192][4096] bf16 (plain: row = g*2048+u)
// ---------------------------------------------------------------------------
__global__ __launch_bounds__(256) void k_convB(
        const float* __restrict__ Wx0, const float* __restrict__ Wx1,
        const float* __restrict__ Wx2, const float* __restrict__ Wx3,
        const float* __restrict__ Wh0, const float* __restrict__ Wh1,
        const float* __restrict__ Wh2, const float* __restrict__ Wh3,
        unsigned short* __restrict__ Bt) {
    __shared__ float tile[64][65];   // +1 pad: <=2-way (free) conflicts
    const int g  = blockIdx.z;
    const int k0 = blockIdx.x * 64;
    const int u0 = blockIdx.y * 64;
    const int t  = threadIdx.x;
    const float* W;
    if (k0 < D_) {
        W = (g == 0 ? Wx0 : g == 1 ? Wx1 : g == 2 ? Wx2 : Wx3) + (size_t)k0 * U_;
    } else {
        W = (g == 0 ? Wh0 : g == 1 ? Wh1 : g == 2 ? Wh2 : Wh3) + (size_t)(k0 - D_) * U_;
    }
    {
        const int kr_b = t >> 4;          // 0..15
        const int uc   = (t & 15) * 4;    // 0..60
        #pragma unroll
        for (int p = 0; p < 4; ++p) {
            int kr = p * 16 + kr_b;
            float4 v = *(const float4*)(W + (size_t)kr * U_ + u0 + uc);
            tile[kr][uc + 0] = v.x;
            tile[kr][uc + 1] = v.y;
            tile[kr][uc + 2] = v.z;
            tile[kr][uc + 3] = v.w;
        }
    }
    __syncthreads();
    {
        const int kc = (t & 7) * 8;       // 0..56
        #pragma unroll
        for (int p = 0; p < 2; ++p) {
            int u_idx = p * 32 + (t >> 3);          // 0..63
            int u = u0 + u_idx;
            int nrow = g * U_ + u;                   // plain mapping
            ushort8 o;
            #pragma unroll
            for (int kk = 0; kk < 8; ++kk)
                o[kk] = f2bf(tile[kc + kk][u_idx]);
            *(ushort8*)(Bt + (size_t)nrow * K_ + k0 + kc) = o;
        }
    }
}

// ---------------------------------------------------------------------------
// Kernel 3: GEMM  Z = Abf * Bt^T — m97 core with BK=64 two-panel unroll:
// two k-panels (each the exact m97 128x32 LDS layout) staged per barrier
// pair, compute runs 2 sub-steps per barrier. Halves barrier count (m132's
// BK=128 failure was the 64KB-LDS occupancy cliff; 32KB keeps cap at 5/CU).
// ---------------------------------------------------------------------------
__device__ __forceinline__ void gload16(const unsigned short* g, unsigned short* l) {
    __builtin_amdgcn_global_load_lds(
        (const __attribute__((address_space(1))) void*)g,
        (__attribute__((address_space(3))) void*)l, 16, 0, 0);
}

__global__ __launch_bounds__(256) void k_gemm(const unsigned short* __restrict__ A,
                                              const unsigned short* __restrict__ Bt,
                                              unsigned short* __restrict__ Z) {
    // XCD-aware swizzle (kept from R4: small win, harmless)
    const int id    = blockIdx.x;
    const int xcd   = id & 7;
    const int s     = id >> 3;
    const int m_blk = (xcd << 2) | (s & 3);   // 0..31
    const int n_blk = s >> 2;                 // 0..63
    const int m0 = m_blk * 128;
    const int n0 = n_blk * 128;

    __shared__ __align__(16) unsigned short As[2][128 * 32];
    __shared__ __align__(16) unsigned short Bs[2][128 * 32];
    const int tid = threadIdx.x;
    const int w   = tid >> 6;      // wave 0..3
    const int l   = tid & 63;      // lane

    const unsigned short* gA = A  + (size_t)(m0 + w * 16 + (l >> 2)) * K_ + (l & 3) * 8;
    const unsigned short* gB = Bt + (size_t)(n0 + w * 16 + (l >> 2)) * K_ + (l & 3) * 8;
    unsigned short* lA0 = As[0] + w * 512;   // wave-uniform LDS bases
    unsigned short* lA1 = As[1] + w * 512;
    unsigned short* lB0 = Bs[0] + w * 512;
    unsigned short* lB1 = Bs[1] + w * 512;

    const int r     = l & 15;
    const int quad  = l >> 4;
    const int m_off = (w & 1) * 64;
    const int n_off = (w >> 1) * 64;

    floatx4 acc[4][4];
    #pragma unroll
    for (int i = 0; i < 4; ++i)
        #pragma unroll
        for (int j = 0; j < 4; ++j)
            #pragma unroll
            for (int e = 0; e < 4; ++e) acc[i][j][e] = 0.f;

    for (int k0 = 0; k0 < K_; k0 += 64) {
        __syncthreads();
        // panel 0: k in [k0, k0+32)
        gload16(gA + k0,                        lA0);
        gload16(gA + k0 + (size_t)64 * K_,      lA0 + 2048);
        gload16(gB + k0,                        lB0);
        gload16(gB + k0 + (size_t)64 * K_,      lB0 + 2048);
        // panel 1: k in [k0+32, k0+64)
        gload16(gA + k0 + 32,                   lA1);
        gload16(gA + k0 + 32 + (size_t)64 * K_, lA1 + 2048);
        gload16(gB + k0 + 32,                   lB1);
        gload16(gB + k0 + 32 + (size_t)64 * K_, lB1 + 2048);
        __syncthreads();

        #pragma unroll
        for (int p = 0; p < 2; ++p) {
            bf16x8 af[4], bfv[4];
            #pragma unroll
            for (int i = 0; i < 4; ++i)
                af[i] = *(const bf16x8*)(As[p] + ((m_off + i * 16 + r) * 32 + quad * 8));
            #pragma unroll
            for (int j = 0; j < 4; ++j)
                bfv[j] = *(const bf16x8*)(Bs[p] + ((n_off + j * 16 + r) * 32 + quad * 8));
            #pragma unroll
            for (int i = 0; i < 4; ++i)
                #pragma unroll
                for (int j = 0; j < 4; ++j)
                    acc[i][j] = __builtin_amdgcn_mfma_f32_16x16x32_bf16(
                        af[i], bfv[j], acc[i][j], 0, 0, 0);
        }
    }

    // epilogue: C/D layout col = lane&15, row = quad*4 + reg  [m89/m91 verified]
    #pragma unroll
    for (int i = 0; i < 4; ++i) {
        #pragma unroll
        for (int j = 0; j < 4; ++j) {
            int col = n0 + n_off + j * 16 + r;
            #pragma unroll
            for (int e = 0; e < 4; ++e) {
                int row = m0 + m_off + i * 16 + quad * 4 + e;
                Z[(size_t)row * N_ + col] = f2bf(acc[i][j][e]);
            }
        }
    }
}

// ---------------------------------------------------------------------------
// Kernel 4: gate fusion. Reads Z(bf16), c, biases; writes h_new, c_new (fp32)
// ---------------------------------------------------------------------------
__global__ void k_gates(const unsigned short* __restrict__ Z, const float* __restrict__ c,
                        const float* __restrict__ bfp, const float* __restrict__ bip,
                        const float* __restrict__ bop, const float* __restrict__ bgp,
                        float* __restrict__ hout, float* __restrict__ cout) {
    int t = blockIdx.x * blockDim.x + threadIdx.x;   // 4 u-values each
    long e = (long)t * 4;
    int b = (int)(e >> 11);      // / 2048
    int u = (int)(e & 2047);
    const size_t zr = (size_t)b * N_;
    ushort4 zf4 = *(const ushort4*)(Z + zr + u);
    ushort4 zi4 = *(const ushort4*)(Z + zr + U_ + u);
    ushort4 zo4 = *(const ushort4*)(Z + zr + 2 * U_ + u);
    ushort4 zg4 = *(const ushort4*)(Z + zr + 3 * U_ + u);
    float4 bfv = *(const float4*)(bfp + u);
    float4 biv = *(const float4*)(bip + u);
    float4 bov = *(const float4*)(bop + u);
    float4 bgv = *(const float4*)(bgp + u);
    float4 cv  = *(const float4*)(c + e);

    float zf[4] = {bf2f(zf4.x), bf2f(zf4.y), bf2f(zf4.z), bf2f(zf4.w)};
    float zi[4] = {bf2f(zi4.x), bf2f(zi4.y), bf2f(zi4.z), bf2f(zi4.w)};
    float zo[4] = {bf2f(zo4.x), bf2f(zo4.y), bf2f(zo4.z), bf2f(zo4.w)};
    float zg[4] = {bf2f(zg4.x), bf2f(zg4.y), bf2f(zg4.z), bf2f(zg4.w)};
    float bff[4] = {bfv.x, bfv.y, bfv.z, bfv.w};
    float bif[4] = {biv.x, biv.y, biv.z, biv.w};
    float bof[4] = {bov.x, bov.y, bov.z, bov.w};
    float bgf[4] = {bgv.x, bgv.y, bgv.z, bgv.w};
    float cf[4]  = {cv.x, cv.y, cv.z, cv.w};

    float hh[4], cc[4];
    #pragma unroll
    for (int q = 0; q < 4; ++q) {
        float f = sigmoid_(zf[q] + bff[q]);
        float i = sigmoid_(zi[q] + bif[q]);
        float o = sigmoid_(zo[q] + bof[q]);
        float g = tanh_(zg[q] + bgf[q]);
        float cn = f * cf[q] + i * g;
        cc[q] = cn;
        hh[q] = o * tanh_(cn);
    }
    float4 ho, co;
    ho.x = hh[0]; ho.y = hh[1]; ho.z = hh[2]; ho.w = hh[3];
    co.x = cc[0]; co.y = cc[1]; co.z = cc[2]; co.w = cc[3];
    *(float4*)(hout + e) = ho;
    *(float4*)(cout + e) = co;
}

// ---------------------------------------------------------------------------
extern "C" void kernel_launch(void* const* d_in, const int* in_sizes, int n_in,
                              void* d_out, int out_size, void* d_ws, size_t ws_size,
                              hipStream_t stream) {
    const float* x   = (const float*)d_in[0];
    const float* h   = (const float*)d_in[1];
    const float* c   = (const float*)d_in[2];
    const float* Wxf = (const float*)d_in[3];
    const float* Wxi = (const float*)d_in[4];
    const float* Wxo = (const float*)d_in[5];
    const float* Wxg = (const float*)d_in[6];
    const float* bf  = (const float*)d_in[7];
    const float* bi  = (const float*)d_in[8];
    const float* bo  = (const float*)d_in[9];
    const float* bg  = (const float*)d_in[10];
    const float* Whf = (const float*)d_in[11];
    const float* Whi = (const float*)d_in[12];
    const float* Who = (const float*)d_in[13];
    const float* Whg = (const float*)d_in[14];
    float* out = (float*)d_out;

    // workspace layout: Abf (33.5 MB) | Bt (67 MB) | Z bf16 (67 MB)
    unsigned short* Abf = (unsigned short*)d_ws;
    unsigned short* Bt  = Abf + (size_t)B_ * K_;
    unsigned short* Z   = Bt + (size_t)N_ * K_;

    k_convA<<<(B_ * K_ / 4) / 256, 256, 0, stream>>>(x, h, Abf);
    k_convB<<<dim3(K_ / 64, U_ / 64, 4), 256, 0, stream>>>(
        Wxf, Wxi, Wxo, Wxg, Whf, Whi, Who, Whg, Bt);
    k_gemm<<<dim3((B_ / 128) * (N_ / 128)), 256, 0, stream>>>(Abf, Bt, Z);
    k_gates<<<(B_ * U_ / 4) / 256, 256, 0, stream>>>(
        Z, c, bf, bi, bo, bg, out, out + (size_t)B_ * U_);
}

// Round 7
// 521.881 us; speedup vs baseline: 1.0657x; 1.0539x over previous
//
#include <hip/hip_runtime.h>
#include <hip/hip_bf16.h>
#include <stdint.h>

#define B_ 4096
#define D_ 2048
#define U_ 2048
#define K_ 4096   // D + U
#define N_ 8192   // 4 * U

typedef __bf16 bf16x8 __attribute__((ext_vector_type(8)));
typedef float floatx4 __attribute__((ext_vector_type(4)));
typedef unsigned short ushort8 __attribute__((ext_vector_type(8)));

__device__ __forceinline__ unsigned short f2bf(float f) {
    union { float f; unsigned int u; } v; v.f = f;
    unsigned int u = v.u;
    unsigned int r = (u + 0x7fffu + ((u >> 16) & 1u)) >> 16;  // round-nearest-even
    return (unsigned short)r;
}

__device__ __forceinline__ float bf2f(unsigned short b) {
    union { unsigned int u; float f; } v;
    v.u = ((unsigned int)b) << 16;
    return v.f;
}

__device__ __forceinline__ float sigmoid_(float x) {
    return 1.0f / (1.0f + __expf(-x));
}
__device__ __forceinline__ float tanh_(float x) {
    return 1.0f - 2.0f / (__expf(2.0f * x) + 1.0f);
}

// ---------------------------------------------------------------------------
// Kernel 1: pack [x | h] -> Abf[4096][4096] bf16 (row-major, K contiguous)
// ---------------------------------------------------------------------------
__global__ void k_convA(const float* __restrict__ x, const float* __restrict__ h,
                        unsigned short* __restrict__ Abf) {
    int t = blockIdx.x * blockDim.x + threadIdx.x;   // one float4 each
    long e = (long)t * 4;
    int b = (int)(e >> 12);       // / 4096
    int k = (int)(e & 4095);
    const float* src = (k < D_) ? (x + (size_t)b * D_ + k)
                                : (h + (size_t)b * U_ + (k - D_));
    float4 v = *(const float4*)src;
    ushort4 o;
    o.x = f2bf(v.x); o.y = f2bf(v.y); o.z = f2bf(v.z); o.w = f2bf(v.w);
    *(ushort4*)(Abf + e) = o;
}

// ---------------------------------------------------------------------------
// Kernel 2: transpose weights -> Bt[8192][4096] bf16 (plain: row = g*2048+u)
// ---------------------------------------------------------------------------
__global__ __launch_bounds__(256) void k_convB(
        const float* __restrict__ Wx0, const float* __restrict__ Wx1,
        const float* __restrict__ Wx2, const float* __restrict__ Wx3,
        const float* __restrict__ Wh0, const float* __restrict__ Wh1,
        const float* __restrict__ Wh2, const float* __restrict__ Wh3,
        unsigned short* __restrict__ Bt) {
    __shared__ float tile[64][65];   // +1 pad: <=2-way (free) conflicts
    const int g  = blockIdx.z;
    const int k0 = blockIdx.x * 64;
    const int u0 = blockIdx.y * 64;
    const int t  = threadIdx.x;
    const float* W;
    if (k0 < D_) {
        W = (g == 0 ? Wx0 : g == 1 ? Wx1 : g == 2 ? Wx2 : Wx3) + (size_t)k0 * U_;
    } else {
        W = (g == 0 ? Wh0 : g == 1 ? Wh1 : g == 2 ? Wh2 : Wh3) + (size_t)(k0 - D_) * U_;
    }
    {
        const int kr_b = t >> 4;          // 0..15
        const int uc   = (t & 15) * 4;    // 0..60
        #pragma unroll
        for (int p = 0; p < 4; ++p) {
            int kr = p * 16 + kr_b;
            float4 v = *(const float4*)(W + (size_t)kr * U_ + u0 + uc);
            tile[kr][uc + 0] = v.x;
            tile[kr][uc + 1] = v.y;
            tile[kr][uc + 2] = v.z;
            tile[kr][uc + 3] = v.w;
        }
    }
    __syncthreads();
    {
        const int kc = (t & 7) * 8;       // 0..56
        #pragma unroll
        for (int p = 0; p < 2; ++p) {
            int u_idx = p * 32 + (t >> 3);          // 0..63
            int u = u0 + u_idx;
            int nrow = g * U_ + u;                   // plain mapping
            ushort8 o;
            #pragma unroll
            for (int kk = 0; kk < 8; ++kk)
                o[kk] = f2bf(tile[kc + kk][u_idx]);
            *(ushort8*)(Bt + (size_t)nrow * K_ + k0 + kc) = o;
        }
    }
}

// ---------------------------------------------------------------------------
// Kernel 3: GEMM  Z = Abf * Bt^T — 256x256 tile, 8 waves (2Mx4N), BK=32,
// 3-deep LDS ring (96 KB), phase-interleaved schedule with COUNTED vmcnt
// (never vmcnt(0) in the main loop), T2 granule-XOR swizzle on the LDS
// tiles (write side pre-swizzles the per-lane global source so the
// global_load_lds destination stays linear — rule #21), T5 setprio around
// each 16-MFMA cluster, T1 XCD-contiguous block swizzle.
//
// Hazard accounting (race-free; audited x3):
//  - tile t computed from buf t%3; tile t+2 staged into buf (t+2)%3, which
//    last held tile t-1 (all waves' reads retired before they passed the
//    previous boundary barrier — lgkmcnt ordering before MFMA issue).
//  - 4 loads/thread staged per tile; s_waitcnt vmcnt(4) at each boundary
//    (asm volatile + "memory": full compiler fence, ds_reads cannot hoist
//    above it) guarantees tile t+1 fully landed; tile t+2's loads stay in
//    flight across the barrier.
// ---------------------------------------------------------------------------
__device__ __forceinline__ void gload16(const unsigned short* g, unsigned short* l) {
    __builtin_amdgcn_global_load_lds(
        (const __attribute__((address_space(1))) void*)g,
        (__attribute__((address_space(3))) void*)l, 16, 0, 0);
}

#define BARRIER() __builtin_amdgcn_s_barrier()

__global__ __launch_bounds__(512, 2) void k_gemm(const unsigned short* __restrict__ A,
                                                 const unsigned short* __restrict__ Bt,
                                                 unsigned short* __restrict__ Z) {
    __shared__ __align__(16) unsigned short sm[3 * 16384];   // 96 KB: 3 x (A 16K + B 16K elems/2)

    // T1: XCD-contiguous chunks; nwg=512, divisible by 8 -> simple swizzle valid
    const int id  = blockIdx.x;
    const int swz = (id & 7) * 64 + (id >> 3);
    const int m0  = (swz & 15) << 8;              // 16 m-blocks
    const int n0  = (swz >> 4) << 8;              // 32 n-blocks

    const int tid  = threadIdx.x;
    const int w    = tid >> 6;        // wave 0..7
    const int l    = tid & 63;
    const int wr   = w >> 2;          // 0..1  (M)
    const int wc   = w & 3;           // 0..3  (N)
    const int r    = l & 15;
    const int quad = l >> 4;
    // T2 read-side swizzle: granule' = quad ^ ((row>>1)&3); row = (...)+r with
    // 16-aligned prefix, so (row>>1)&3 == (r>>1)&3 — per-lane constant.
    const int sw8  = (quad ^ ((r >> 1) & 3)) << 3;

    const int aBase = (wr * 128 + r) * 32 + sw8;          // elems within buffer
    const int bBase = 8192 + (wc * 64 + r) * 32 + sw8;

    // staging: thread covers one 16B slot per region; regions: A-lo,A-hi,B-lo,B-hi
    const int srow = tid >> 2;                            // 0..127 within region
    const int sg   = (((tid & 3) ^ ((srow >> 1) & 3)) << 3);  // pre-swizzled source granule
    const unsigned short* gA0 = A  + (size_t)(m0 + srow      ) * K_ + sg;
    const unsigned short* gA1 = A  + (size_t)(m0 + 128 + srow) * K_ + sg;
    const unsigned short* gB0 = Bt + (size_t)(n0 + srow      ) * K_ + sg;
    const unsigned short* gB1 = Bt + (size_t)(n0 + 128 + srow) * K_ + sg;
    unsigned short* const stw = sm + w * 512;   // + buf*16384 + region*4096; HW adds lane*16B

    floatx4 acc[8][4];
    #pragma unroll
    for (int i = 0; i < 8; ++i)
        #pragma unroll
        for (int j = 0; j < 4; ++j)
            #pragma unroll
            for (int e = 0; e < 4; ++e) acc[i][j][e] = 0.f;

    // prologue: stage tiles 0,1 into bufs 0,1; wait tile 0 (vmcnt 8 -> 4)
    #pragma unroll
    for (int tt = 0; tt < 2; ++tt) {
        unsigned short* b = stw + tt * 16384;
        const int kt = tt * 32;
        gload16(gA0 + kt, b);
        gload16(gA1 + kt, b + 4096);
        gload16(gB0 + kt, b + 8192);
        gload16(gB1 + kt, b + 12288);
    }
    asm volatile("s_waitcnt vmcnt(4)" ::: "memory");
    BARRIER();

    int c = 0;
    for (int t = 0; t < 128; ++t) {
        const unsigned short* Sb = sm + c * 16384;
        const int cst = (c == 0) ? 2 : c - 1;             // == (t+2)%3
        unsigned short* sb = stw + cst * 16384;
        const int kt = (t + 2) * 32;
        const bool st = (t < 126);

        bf16x8 bq[4], aq[4];
        // ---- phase 0: read B frags (cached for both phases) + A i=0..3,
        //               stage A halves of tile t+2, 16 MFMA ----
        #pragma unroll
        for (int j = 0; j < 4; ++j) bq[j] = *(const bf16x8*)(Sb + bBase + j * 512);
        #pragma unroll
        for (int i = 0; i < 4; ++i) aq[i] = *(const bf16x8*)(Sb + aBase + i * 512);
        if (st) { gload16(gA0 + kt, sb); gload16(gA1 + kt, sb + 4096); }
        BARRIER();
        __builtin_amdgcn_s_setprio(1);
        #pragma unroll
        for (int i = 0; i < 4; ++i)
            #pragma unroll
            for (int j = 0; j < 4; ++j)
                acc[i][j] = __builtin_amdgcn_mfma_f32_16x16x32_bf16(
                    aq[i], bq[j], acc[i][j], 0, 0, 0);
        __builtin_amdgcn_s_setprio(0);
        BARRIER();

        // ---- phase 1: read A i=4..7, stage B halves of tile t+2, 16 MFMA ----
        #pragma unroll
        for (int i = 0; i < 4; ++i) aq[i] = *(const bf16x8*)(Sb + aBase + (i + 4) * 512);
        if (st) { gload16(gB0 + kt, sb + 8192); gload16(gB1 + kt, sb + 12288); }
        BARRIER();
        __builtin_amdgcn_s_setprio(1);
        #pragma unroll
        for (int i = 0; i < 4; ++i)
            #pragma unroll
            for (int j = 0; j < 4; ++j)
                acc[i + 4][j] = __builtin_amdgcn_mfma_f32_16x16x32_bf16(
                    aq[i], bq[j], acc[i + 4][j], 0, 0, 0);
        __builtin_amdgcn_s_setprio(0);
        // boundary: counted vmcnt — tile t+1 landed, tile t+2 stays in flight
        if (st) asm volatile("s_waitcnt vmcnt(4)" ::: "memory");
        else    asm volatile("s_waitcnt vmcnt(0)" ::: "memory");
        BARRIER();

        c = (c == 2) ? 0 : c + 1;
    }

    // epilogue: C/D layout col = lane&15, row = quad*4 + reg  [m89/m91 verified]
    #pragma unroll
    for (int i = 0; i < 8; ++i) {
        #pragma unroll
        for (int j = 0; j < 4; ++j) {
            const int col = n0 + wc * 64 + j * 16 + r;
            #pragma unroll
            for (int e = 0; e < 4; ++e) {
                const int row = m0 + wr * 128 + i * 16 + quad * 4 + e;
                Z[(size_t)row * N_ + col] = f2bf(acc[i][j][e]);
            }
        }
    }
}

// ---------------------------------------------------------------------------
// Kernel 4: gate fusion. Reads Z(bf16), c, biases; writes h_new, c_new (fp32)
// ---------------------------------------------------------------------------
__global__ void k_gates(const unsigned short* __restrict__ Z, const float* __restrict__ c,
                        const float* __restrict__ bfp, const float* __restrict__ bip,
                        const float* __restrict__ bop, const float* __restrict__ bgp,
                        float* __restrict__ hout, float* __restrict__ cout) {
    int t = blockIdx.x * blockDim.x + threadIdx.x;   // 4 u-values each
    long e = (long)t * 4;
    int b = (int)(e >> 11);      // / 2048
    int u = (int)(e & 2047);
    const size_t zr = (size_t)b * N_;
    ushort4 zf4 = *(const ushort4*)(Z + zr + u);
    ushort4 zi4 = *(const ushort4*)(Z + zr + U_ + u);
    ushort4 zo4 = *(const ushort4*)(Z + zr + 2 * U_ + u);
    ushort4 zg4 = *(const ushort4*)(Z + zr + 3 * U_ + u);
    float4 bfv = *(const float4*)(bfp + u);
    float4 biv = *(const float4*)(bip + u);
    float4 bov = *(const float4*)(bop + u);
    float4 bgv = *(const float4*)(bgp + u);
    float4 cv  = *(const float4*)(c + e);

    float zf[4] = {bf2f(zf4.x), bf2f(zf4.y), bf2f(zf4.z), bf2f(zf4.w)};
    float zi[4] = {bf2f(zi4.x), bf2f(zi4.y), bf2f(zi4.z), bf2f(zi4.w)};
    float zo[4] = {bf2f(zo4.x), bf2f(zo4.y), bf2f(zo4.z), bf2f(zo4.w)};
    float zg[4] = {bf2f(zg4.x), bf2f(zg4.y), bf2f(zg4.z), bf2f(zg4.w)};
    float bff[4] = {bfv.x, bfv.y, bfv.z, bfv.w};
    float bif[4] = {biv.x, biv.y, biv.z, biv.w};
    float bof[4] = {bov.x, bov.y, bov.z, bov.w};
    float bgf[4] = {bgv.x, bgv.y, bgv.z, bgv.w};
    float cf[4]  = {cv.x, cv.y, cv.z, cv.w};

    float hh[4], cc[4];
    #pragma unroll
    for (int q = 0; q < 4; ++q) {
        float f = sigmoid_(zf[q] + bff[q]);
        float i = sigmoid_(zi[q] + bif[q]);
        float o = sigmoid_(zo[q] + bof[q]);
        float g = tanh_(zg[q] + bgf[q]);
        float cn = f * cf[q] + i * g;
        cc[q] = cn;
        hh[q] = o * tanh_(cn);
    }
    float4 ho, co;
    ho.x = hh[0]; ho.y = hh[1]; ho.z = hh[2]; ho.w = hh[3];
    co.x = cc[0]; co.y = cc[1]; co.z = cc[2]; co.w = cc[3];
    *(float4*)(hout + e) = ho;
    *(float4*)(cout + e) = co;
}

// ---------------------------------------------------------------------------
extern "C" void kernel_launch(void* const* d_in, const int* in_sizes, int n_in,
                              void* d_out, int out_size, void* d_ws, size_t ws_size,
                              hipStream_t stream) {
    const float* x   = (const float*)d_in[0];
    const float* h   = (const float*)d_in[1];
    const float* c   = (const float*)d_in[2];
    const float* Wxf = (const float*)d_in[3];
    const float* Wxi = (const float*)d_in[4];
    const float* Wxo = (const float*)d_in[5];
    const float* Wxg = (const float*)d_in[6];
    const float* bf  = (const float*)d_in[7];
    const float* bi  = (const float*)d_in[8];
    const float* bo  = (const float*)d_in[9];
    const float* bg  = (const float*)d_in[10];
    const float* Whf = (const float*)d_in[11];
    const float* Whi = (const float*)d_in[12];
    const float* Who = (const float*)d_in[13];
    const float* Whg = (const float*)d_in[14];
    float* out = (float*)d_out;

    // workspace layout: Abf (33.5 MB) | Bt (67 MB) | Z bf16 (67 MB)
    unsigned short* Abf = (unsigned short*)d_ws;
    unsigned short* Bt  = Abf + (size_t)B_ * K_;
    unsigned short* Z   = Bt + (size_t)N_ * K_;

    k_convA<<<(B_ * K_ / 4) / 256, 256, 0, stream>>>(x, h, Abf);
    k_convB<<<dim3(K_ / 64, U_ / 64, 4), 256, 0, stream>>>(
        Wxf, Wxi, Wxo, Wxg, Whf, Whi, Who, Whg, Bt);
    k_gemm<<<dim3((B_ / 256) * (N_ / 256)), 512, 0, stream>>>(Abf, Bt, Z);
    k_gates<<<(B_ * U_ / 4) / 256, 256, 0, stream>>>(
        Z, c, bf, bi, bo, bg, out, out + (size_t)B_ * U_);
}

// Round 8
// 503.896 us; speedup vs baseline: 1.1038x; 1.0357x over previous
//
#include <hip/hip_runtime.h>
#include <hip/hip_bf16.h>
#include <stdint.h>

#define B_ 4096
#define D_ 2048
#define U_ 2048
#define K_ 4096   // D + U
#define N_ 8192   // 4 * U

typedef __bf16 bf16x8 __attribute__((ext_vector_type(8)));
typedef float floatx4 __attribute__((ext_vector_type(4)));
typedef unsigned short ushort8 __attribute__((ext_vector_type(8)));

__device__ __forceinline__ unsigned short f2bf(float f) {
    union { float f; unsigned int u; } v; v.f = f;
    unsigned int u = v.u;
    unsigned int r = (u + 0x7fffu + ((u >> 16) & 1u)) >> 16;  // round-nearest-even
    return (unsigned short)r;
}

__device__ __forceinline__ float bf2f(unsigned short b) {
    union { unsigned int u; float f; } v;
    v.u = ((unsigned int)b) << 16;
    return v.f;
}

__device__ __forceinline__ float sigmoid_(float x) {
    return 1.0f / (1.0f + __expf(-x));
}
__device__ __forceinline__ float tanh_(float x) {
    return 1.0f - 2.0f / (__expf(2.0f * x) + 1.0f);
}

// ---------------------------------------------------------------------------
// Kernel 1: pack [x | h] -> Abf[4096][4096] bf16 (row-major, K contiguous)
// ---------------------------------------------------------------------------
__global__ void k_convA(const float* __restrict__ x, const float* __restrict__ h,
                        unsigned short* __restrict__ Abf) {
    int t = blockIdx.x * blockDim.x + threadIdx.x;   // one float4 each
    long e = (long)t * 4;
    int b = (int)(e >> 12);       // / 4096
    int k = (int)(e & 4095);
    const float* src = (k < D_) ? (x + (size_t)b * D_ + k)
                                : (h + (size_t)b * U_ + (k - D_));
    float4 v = *(const float4*)src;
    ushort4 o;
    o.x = f2bf(v.x); o.y = f2bf(v.y); o.z = f2bf(v.z); o.w = f2bf(v.w);
    *(ushort4*)(Abf + e) = o;
}

// ---------------------------------------------------------------------------
// Kernel 2: transpose weights -> Bt[8192][4096] bf16 (plain: row = g*2048+u)
// ---------------------------------------------------------------------------
__global__ __launch_bounds__(256) void k_convB(
        const float* __restrict__ Wx0, const float* __restrict__ Wx1,
        const float* __restrict__ Wx2, const float* __restrict__ Wx3,
        const float* __restrict__ Wh0, const float* __restrict__ Wh1,
        const float* __restrict__ Wh2, const float* __restrict__ Wh3,
        unsigned short* __restrict__ Bt) {
    __shared__ float tile[64][65];   // +1 pad: <=2-way (free) conflicts
    const int g  = blockIdx.z;
    const int k0 = blockIdx.x * 64;
    const int u0 = blockIdx.y * 64;
    const int t  = threadIdx.x;
    const float* W;
    if (k0 < D_) {
        W = (g == 0 ? Wx0 : g == 1 ? Wx1 : g == 2 ? Wx2 : Wx3) + (size_t)k0 * U_;
    } else {
        W = (g == 0 ? Wh0 : g == 1 ? Wh1 : g == 2 ? Wh2 : Wh3) + (size_t)(k0 - D_) * U_;
    }
    {
        const int kr_b = t >> 4;          // 0..15
        const int uc   = (t & 15) * 4;    // 0..60
        #pragma unroll
        for (int p = 0; p < 4; ++p) {
            int kr = p * 16 + kr_b;
            float4 v = *(const float4*)(W + (size_t)kr * U_ + u0 + uc);
            tile[kr][uc + 0] = v.x;
            tile[kr][uc + 1] = v.y;
            tile[kr][uc + 2] = v.z;
            tile[kr][uc + 3] = v.w;
        }
    }
    __syncthreads();
    {
        const int kc = (t & 7) * 8;       // 0..56
        #pragma unroll
        for (int p = 0; p < 2; ++p) {
            int u_idx = p * 32 + (t >> 3);          // 0..63
            int u = u0 + u_idx;
            int nrow = g * U_ + u;                   // plain mapping
            ushort8 o;
            #pragma unroll
            for (int kk = 0; kk < 8; ++kk)
                o[kk] = f2bf(tile[kc + kk][u_idx]);
            *(ushort8*)(Bt + (size_t)nrow * K_ + k0 + kc) = o;
        }
    }
}

// ---------------------------------------------------------------------------
// Kernel 3: GEMM  Z = Abf * Bt^T — 256x256 tile, 8 waves (2Mx4N), BK=32,
// 3-deep LDS ring (96 KB). R8 change: SINGLE-PHASE K-tile. R7 measured
// 2475 cyc/tile vs 1240 MFMA floor (MfmaUtil 47%) — the 4 barriers/tile +
// 2 exposed ds_read windows were the gap. Now per tile: 12 ds_reads +
// 4 stage loads -> one 32-MFMA cluster (all independent; compiler's
// fine-grained lgkmcnt gates first-8-read MFMAs while last 4 land under
// them) -> vmcnt(4) -> barrier. 128 barriers total (was 512).
// Cross-wave staging visibility (validated R7): each wave retires its OWN
// stage loads (vmcnt) BEFORE the barrier; reads happen after it.
// T2 granule-XOR swizzle (bank-conflict 3.35e7 -> 0, R7-verified),
// T5 setprio, T1 XCD swizzle retained.
// ---------------------------------------------------------------------------
__device__ __forceinline__ void gload16(const unsigned short* g, unsigned short* l) {
    __builtin_amdgcn_global_load_lds(
        (const __attribute__((address_space(1))) void*)g,
        (__attribute__((address_space(3))) void*)l, 16, 0, 0);
}

#define BARRIER() __builtin_amdgcn_s_barrier()

__global__ __launch_bounds__(512, 2) void k_gemm(const unsigned short* __restrict__ A,
                                                 const unsigned short* __restrict__ Bt,
                                                 unsigned short* __restrict__ Z) {
    __shared__ __align__(16) unsigned short sm[3 * 16384];   // 96 KB

    // T1: XCD-contiguous chunks; nwg=512, divisible by 8 -> simple swizzle valid
    const int id  = blockIdx.x;
    const int swz = (id & 7) * 64 + (id >> 3);
    const int m0  = (swz & 15) << 8;              // 16 m-blocks
    const int n0  = (swz >> 4) << 8;              // 32 n-blocks

    const int tid  = threadIdx.x;
    const int w    = tid >> 6;        // wave 0..7
    const int l    = tid & 63;
    const int wr   = w >> 2;          // 0..1  (M)
    const int wc   = w & 3;           // 0..3  (N)
    const int r    = l & 15;
    const int quad = l >> 4;
    // T2 read-side swizzle: granule' = quad ^ ((row>>1)&3); row has 16-aligned
    // prefix + r, so (row>>1)&3 == (r>>1)&3 — per-lane constant.
    const int sw8  = (quad ^ ((r >> 1) & 3)) << 3;

    const int aBase = (wr * 128 + r) * 32 + sw8;          // elems within buffer
    const int bBase = 8192 + (wc * 64 + r) * 32 + sw8;

    // staging: thread covers one 16B slot per region; regions: A-lo,A-hi,B-lo,B-hi
    const int srow = tid >> 2;                            // 0..127 within region
    const int sg   = (((tid & 3) ^ ((srow >> 1) & 3)) << 3);  // pre-swizzled source granule
    const unsigned short* gA0 = A  + (size_t)(m0 + srow      ) * K_ + sg;
    const unsigned short* gA1 = A  + (size_t)(m0 + 128 + srow) * K_ + sg;
    const unsigned short* gB0 = Bt + (size_t)(n0 + srow      ) * K_ + sg;
    const unsigned short* gB1 = Bt + (size_t)(n0 + 128 + srow) * K_ + sg;
    unsigned short* const stw = sm + w * 512;   // + buf*16384 + region*4096; HW adds lane*16B

    floatx4 acc[8][4];
    #pragma unroll
    for (int i = 0; i < 8; ++i)
        #pragma unroll
        for (int j = 0; j < 4; ++j)
            #pragma unroll
            for (int e = 0; e < 4; ++e) acc[i][j][e] = 0.f;

    // prologue: stage tiles 0,1 into bufs 0,1; wait tile 0 (vmcnt 8 -> 4)
    #pragma unroll
    for (int tt = 0; tt < 2; ++tt) {
        unsigned short* b = stw + tt * 16384;
        const int kt = tt * 32;
        gload16(gA0 + kt, b);
        gload16(gA1 + kt, b + 4096);
        gload16(gB0 + kt, b + 8192);
        gload16(gB1 + kt, b + 12288);
    }
    asm volatile("s_waitcnt vmcnt(4)" ::: "memory");
    BARRIER();

    int c = 0;
    for (int t = 0; t < 128; ++t) {
        const unsigned short* Sb = sm + c * 16384;
        const int cst = (c == 0) ? 2 : c - 1;             // == (t+2)%3
        unsigned short* sb = stw + cst * 16384;
        const int kt = (t + 2) * 32;
        const bool st = (t < 126);

        // ---- single phase: all fragment reads, then stage, then 32 MFMA ----
        bf16x8 bq[4], aq[8];
        #pragma unroll
        for (int j = 0; j < 4; ++j) bq[j] = *(const bf16x8*)(Sb + bBase + j * 512);
        #pragma unroll
        for (int i = 0; i < 8; ++i) aq[i] = *(const bf16x8*)(Sb + aBase + i * 512);
        if (st) {
            gload16(gA0 + kt, sb);
            gload16(gA1 + kt, sb + 4096);
            gload16(gB0 + kt, sb + 8192);
            gload16(gB1 + kt, sb + 12288);
        }
        __builtin_amdgcn_s_setprio(1);
        #pragma unroll
        for (int i = 0; i < 8; ++i)
            #pragma unroll
            for (int j = 0; j < 4; ++j)
                acc[i][j] = __builtin_amdgcn_mfma_f32_16x16x32_bf16(
                    aq[i], bq[j], acc[i][j], 0, 0, 0);
        __builtin_amdgcn_s_setprio(0);
        // boundary: counted vmcnt BEFORE barrier (cross-wave visibility chain)
        if (st) asm volatile("s_waitcnt vmcnt(4)" ::: "memory");
        else    asm volatile("s_waitcnt vmcnt(0)" ::: "memory");
        BARRIER();

        c = (c == 2) ? 0 : c + 1;
    }

    // epilogue: C/D layout col = lane&15, row = quad*4 + reg  [m89/m91 verified]
    #pragma unroll
    for (int i = 0; i < 8; ++i) {
        #pragma unroll
        for (int j = 0; j < 4; ++j) {
            const int col = n0 + wc * 64 + j * 16 + r;
            #pragma unroll
            for (int e = 0; e < 4; ++e) {
                const int row = m0 + wr * 128 + i * 16 + quad * 4 + e;
                Z[(size_t)row * N_ + col] = f2bf(acc[i][j][e]);
            }
        }
    }
}

// ---------------------------------------------------------------------------
// Kernel 4: gate fusion. Reads Z(bf16), c, biases; writes h_new, c_new (fp32)
// ---------------------------------------------------------------------------
__global__ void k_gates(const unsigned short* __restrict__ Z, const float* __restrict__ c,
                        const float* __restrict__ bfp, const float* __restrict__ bip,
                        const float* __restrict__ bop, const float* __restrict__ bgp,
                        float* __restrict__ hout, float* __restrict__ cout) {
    int t = blockIdx.x * blockDim.x + threadIdx.x;   // 4 u-values each
    long e = (long)t * 4;
    int b = (int)(e >> 11);      // / 2048
    int u = (int)(e & 2047);
    const size_t zr = (size_t)b * N_;
    ushort4 zf4 = *(const ushort4*)(Z + zr + u);
    ushort4 zi4 = *(const ushort4*)(Z + zr + U_ + u);
    ushort4 zo4 = *(const ushort4*)(Z + zr + 2 * U_ + u);
    ushort4 zg4 = *(const ushort4*)(Z + zr + 3 * U_ + u);
    float4 bfv = *(const float4*)(bfp + u);
    float4 biv = *(const float4*)(bip + u);
    float4 bov = *(const float4*)(bop + u);
    float4 bgv = *(const float4*)(bgp + u);
    float4 cv  = *(const float4*)(c + e);

    float zf[4] = {bf2f(zf4.x), bf2f(zf4.y), bf2f(zf4.z), bf2f(zf4.w)};
    float zi[4] = {bf2f(zi4.x), bf2f(zi4.y), bf2f(zi4.z), bf2f(zi4.w)};
    float zo[4] = {bf2f(zo4.x), bf2f(zo4.y), bf2f(zo4.z), bf2f(zo4.w)};
    float zg[4] = {bf2f(zg4.x), bf2f(zg4.y), bf2f(zg4.z), bf2f(zg4.w)};
    float bff[4] = {bfv.x, bfv.y, bfv.z, bfv.w};
    float bif[4] = {biv.x, biv.y, biv.z, biv.w};
    float bof[4] = {bov.x, bov.y, bov.z, bov.w};
    float bgf[4] = {bgv.x, bgv.y, bgv.z, bgv.w};
    float cf[4]  = {cv.x, cv.y, cv.z, cv.w};

    float hh[4], cc[4];
    #pragma unroll
    for (int q = 0; q < 4; ++q) {
        float f = sigmoid_(zf[q] + bff[q]);
        float i = sigmoid_(zi[q] + bif[q]);
        float o = sigmoid_(zo[q] + bof[q]);
        float g = tanh_(zg[q] + bgf[q]);
        float cn = f * cf[q] + i * g;
        cc[q] = cn;
        hh[q] = o * tanh_(cn);
    }
    float4 ho, co;
    ho.x = hh[0]; ho.y = hh[1]; ho.z = hh[2]; ho.w = hh[3];
    co.x = cc[0]; co.y = cc[1]; co.z = cc[2]; co.w = cc[3];
    *(float4*)(hout + e) = ho;
    *(float4*)(cout + e) = co;
}

// ---------------------------------------------------------------------------
extern "C" void kernel_launch(void* const* d_in, const int* in_sizes, int n_in,
                              void* d_out, int out_size, void* d_ws, size_t ws_size,
                              hipStream_t stream) {
    const float* x   = (const float*)d_in[0];
    const float* h   = (const float*)d_in[1];
    const float* c   = (const float*)d_in[2];
    const float* Wxf = (const float*)d_in[3];
    const float* Wxi = (const float*)d_in[4];
    const float* Wxo = (const float*)d_in[5];
    const float* Wxg = (const float*)d_in[6];
    const float* bf  = (const float*)d_in[7];
    const float* bi  = (const float*)d_in[8];
    const float* bo  = (const float*)d_in[9];
    const float* bg  = (const float*)d_in[10];
    const float* Whf = (const float*)d_in[11];
    const float* Whi = (const float*)d_in[12];
    const float* Who = (const float*)d_in[13];
    const float* Whg = (const float*)d_in[14];
    float* out = (float*)d_out;

    // workspace layout: Abf (33.5 MB) | Bt (67 MB) | Z bf16 (67 MB)
    unsigned short* Abf = (unsigned short*)d_ws;
    unsigned short* Bt  = Abf + (size_t)B_ * K_;
    unsigned short* Z   = Bt + (size_t)N_ * K_;

    k_convA<<<(B_ * K_ / 4) / 256, 256, 0, stream>>>(x, h, Abf);
    k_convB<<<dim3(K_ / 64, U_ / 64, 4), 256, 0, stream>>>(
        Wxf, Wxi, Wxo, Wxg, Whf, Whi, Who, Whg, Bt);
    k_gemm<<<dim3((B_ / 256) * (N_ / 256)), 512, 0, stream>>>(Abf, Bt, Z);
    k_gates<<<(B_ * U_ / 4) / 256, 256, 0, stream>>>(
        Z, c, bf, bi, bo, bg, out, out + (size_t)B_ * U_);
}